// Round 18
// baseline (270.849 us; speedup 1.0000x reference)
//
#include <hip/hip_runtime.h>
#include <hip/hip_bf16.h>

#define N_NODES 50000
#define N_EDGES 800000
#define N_GRAPHS 500
#define H 90
#define PSTRIDE 96     // plane row stride (u16) -> 192 B; 48 u32 per row
#define SGROWS 8
#define CAP 64         // bucket capacity; P(deg>64) ~ 1e-40 for Poisson(16)
#define NG32 ((N_NODES + 31) / 32)      // 1563

typedef __attribute__((ext_vector_type(8))) short bf16x8;
typedef __attribute__((ext_vector_type(8))) unsigned short u16x8;
typedef __attribute__((ext_vector_type(4))) float f32x4;

__device__ __forceinline__ void pack_split(float v, unsigned short& h16, unsigned short& l16) {
    unsigned u = __float_as_uint(v);
    unsigned hi = (u + 0x7fffu + ((u >> 16) & 1u)) & 0xffff0000u;
    float lo = v - __uint_as_float(hi);
    unsigned ul = __float_as_uint(lo);
    h16 = (unsigned short)(hi >> 16);
    l16 = (unsigned short)((ul + 0x7fffu + ((ul >> 16) & 1u)) >> 16);
}
__device__ __forceinline__ unsigned short pack_hi(float v) {   // RNE to bf16
    unsigned u = __float_as_uint(v);
    return (unsigned short)((u + 0x7fffu + ((u >> 16) & 1u)) >> 16);
}
__device__ __forceinline__ float bfu_lo(unsigned v) { return __uint_as_float(v << 16); }
__device__ __forceinline__ float bfu_hi(unsigned v) { return __uint_as_float(v & 0xffff0000u); }

// XOR-swizzled byte offset within LDS W tile (row stride 192 B)
__device__ __forceinline__ int wswz(int row, int byteInRow) {
    return (row * 192 + byteInRow) ^ ((row & 7) << 4);
}

// ================= conversions =================
__global__ __launch_bounds__(256) void convert_x_kernel(const float* __restrict__ x,
                                                        unsigned short* __restrict__ xh) {
    int n0 = blockIdx.x * 32;
    for (int idx = threadIdx.x; idx < 32 * PSTRIDE; idx += 256) {
        int r = idx / PSTRIDE, c = idx - r * PSTRIDE;
        int n = n0 + r;
        if (n >= N_NODES) continue;
        unsigned short h16 = 0;
        if (c < H) h16 = pack_hi(x[(size_t)n * H + c]);
        __builtin_nontemporal_store(h16, &xh[(size_t)n * PSTRIDE + c]);
    }
}

__global__ __launch_bounds__(256) void convert_w_kernel(const float* __restrict__ w0,
                                                        const float* __restrict__ w1,
                                                        const float* __restrict__ w2,
                                                        const float* __restrict__ w3,
                                                        const float* __restrict__ w4,
                                                        const float* __restrict__ w5,
                                                        unsigned short* __restrict__ wbuf) {
    int m = blockIdx.y;
    const float* src = (m == 0) ? w0 : (m == 1) ? w1 : (m == 2) ? w2
                     : (m == 3) ? w3 : (m == 4) ? w4 : w5;
    unsigned short* dhi = wbuf + (size_t)m * 2 * 96 * 96;
    unsigned short* dlo = dhi + 96 * 96;
    int idx = blockIdx.x * blockDim.x + threadIdx.x;
    if (idx < 96 * 96) {
        int r = idx / 96, c = idx - r * 96;
        float v = (r < H && c < H) ? src[r * H + c] : 0.0f;
        unsigned short h16, l16;
        pack_split(v, h16, l16);
        dhi[idx] = h16;
        dlo[idx] = l16;
    }
}

// ================= one-pass bucket CSR build (no deg/scan) =================
#define FCHUNKS 128
__global__ __launch_bounds__(256) void fill_bucket_kernel(const int* __restrict__ src,
                                                          const int* __restrict__ dst,
                                                          int* __restrict__ cnt,
                                                          unsigned short* __restrict__ csr) {
    const int PART_SZ = N_NODES / 8;
    const int ECH = (N_EDGES + FCHUNKS - 1) / FCHUNKS;
    int p = blockIdx.x & 7;
    int chunk = blockIdx.x >> 3;
    int e0 = chunk * ECH;
    int e1 = min(e0 + ECH, N_EDGES);
    int lo = p * PART_SZ;
    int hi = lo + PART_SZ;
    for (int e = e0 + threadIdx.x; e < e1; e += 256) {
        int d = dst[e];
        if (d >= lo && d < hi) {
            int pos = atomicAdd(&cnt[d], 1);
            if (pos < CAP)
                __builtin_nontemporal_store((unsigned short)src[e],
                                            &csr[(size_t)d * CAP + pos]);
        }
    }
}

// ================= aggregation: 16-deep-unrolled bucket gather, hi-plane only =================
__global__ __launch_bounds__(256) void aggregate_kernel(const unsigned* __restrict__ xhi32,
                                                        const int* __restrict__ cnt,
                                                        const unsigned short* __restrict__ csr,
                                                        unsigned* __restrict__ ahi32) {
    int wv = threadIdx.x >> 6;
    int lane = threadIdx.x & 63;
    int n = blockIdx.x * 4 + wv;           // 12500*4 = 50000 exact

    bool act = lane < 45;
    int L = act ? lane : 44;
    int deg = cnt[n];
    int nd = min(deg, CAP);
    const unsigned short* row = csr + (size_t)n * CAP;

    float a0 = 0.0f, a1 = 0.0f;
    int j = 0;
    for (; j + 15 < nd; j += 16) {
        unsigned v[16];
#pragma unroll
        for (int q = 0; q < 16; ++q) v[q] = xhi32[(size_t)row[j + q] * 48 + L];
#pragma unroll
        for (int q = 0; q < 16; ++q) { a0 += bfu_lo(v[q]); a1 += bfu_hi(v[q]); }
    }
    for (; j + 7 < nd; j += 8) {
        unsigned v[8];
#pragma unroll
        for (int q = 0; q < 8; ++q) v[q] = xhi32[(size_t)row[j + q] * 48 + L];
#pragma unroll
        for (int q = 0; q < 8; ++q) { a0 += bfu_lo(v[q]); a1 += bfu_hi(v[q]); }
    }
    for (; j + 3 < nd; j += 4) {
        unsigned v[4];
#pragma unroll
        for (int q = 0; q < 4; ++q) v[q] = xhi32[(size_t)row[j + q] * 48 + L];
#pragma unroll
        for (int q = 0; q < 4; ++q) { a0 += bfu_lo(v[q]); a1 += bfu_hi(v[q]); }
    }
    for (; j < nd; ++j) {
        unsigned v = xhi32[(size_t)row[j] * 48 + L];
        a0 += bfu_lo(v);
        a1 += bfu_hi(v);
    }

    if (lane < 48) {
        unsigned vh = 0u;
        if (act) {
            float inv = 1.0f / (float)max(deg, 1);
            unsigned short h0 = pack_hi(a0 * inv);
            unsigned short h1 = pack_hi(a1 * inv);
            vh = (unsigned)h0 | ((unsigned)h1 << 16);
        }
        __builtin_nontemporal_store(vh, &ahi32[(size_t)n * 48 + lane]);
    }
}

// ================= combine: r15-proven (256 thr, A hi-only, W hi LDS + lo L2) =================
// Output planes written non-temporally (bypass L2 -> no probe-flush for next consumer).
template<int MODE>
__global__ __launch_bounds__(256) void combine_kernel(
        const unsigned short* __restrict__ aghi,
        const unsigned short* __restrict__ xhi,
        const unsigned short* __restrict__ wl,   // hi plane then lo plane (96*96 each)
        const unsigned short* __restrict__ wr,
        const float* __restrict__ bias,
        unsigned short* __restrict__ ohi,
        const int* __restrict__ batch, float* __restrict__ gs) {
    __shared__ unsigned short sWlh[96 * 96];   // XOR-swizzled, row stride 192 B
    __shared__ unsigned short sWrh[96 * 96];
    __shared__ float SG[SGROWS * 96];

    const int tid = threadIdx.x;
    const int lane = tid & 63;
    const int wv = tid >> 6;
    const int nhalf = wv >> 1;
    const int hhalf = wv & 1;
    const int blk0 = blockIdx.x * 32;
    const int node0 = blk0 + nhalf * 16;
    const int col = lane & 15;
    const int kq = lane >> 4;
    const int tbase = hhalf * 3;
    const int nA = min(node0 + col, N_NODES - 1);

    // ---- hoist A loads (6 x 16B, in flight through staging + barrier) ----
    bf16x8 Gh[3], Xh[3];
#pragma unroll
    for (int ks = 0; ks < 3; ++ks) {
        size_t aoff = (size_t)nA * PSTRIDE + ks * 32 + kq * 8;
        Gh[ks] = *reinterpret_cast<const bf16x8*>(aghi + aoff);
        Xh[ks] = *reinterpret_cast<const bf16x8*>(xhi + aoff);
    }

    if (MODE == 2)
        for (int i = tid; i < SGROWS * 96; i += 256) SG[i] = 0.0f;

    // ---- stage BOTH W hi planes into LDS (2 x 18.4 KB) ----
    for (int idx = tid; idx < 96 * 12; idx += 256) {
        int r = idx / 12, c8 = idx - r * 12;
        u16x8 a = *reinterpret_cast<const u16x8*>(wl + r * 96 + c8 * 8);
        u16x8 b = *reinterpret_cast<const u16x8*>(wr + r * 96 + c8 * 8);
        *(u16x8*)((char*)sWlh + wswz(r, c8 * 16)) = a;
        *(u16x8*)((char*)sWrh + wswz(r, c8 * 16)) = b;
    }
    __syncthreads();   // the ONLY barrier in the main path

    float bv[3];
#pragma unroll
    for (int t = 0; t < 3; ++t) {
        int h = (tbase + t) * 16 + col;
        bv[t] = (h < H) ? bias[h] : 0.0f;
    }

    f32x4 acc[3] = {};

#pragma unroll
    for (int pass = 0; pass < 2; ++pass) {
        const unsigned short* wlo = (pass ? wr : wl) + 96 * 96;   // lo plane, from L2
        const unsigned short* sH = pass ? sWrh : sWlh;
#pragma unroll
        for (int ks = 0; ks < 3; ++ks) {
            const bf16x8 Ah = pass ? Xh[ks] : Gh[ks];
            const int kb = ks * 64 + kq * 16;    // byte offset in LDS row
            bf16x8 Bh[3], Bl[3];
#pragma unroll
            for (int t = 0; t < 3; ++t) {
                int wrow = (tbase + t) * 16 + col;
                Bh[t] = *(const bf16x8*)((const char*)sH + wswz(wrow, kb));
                Bl[t] = *reinterpret_cast<const bf16x8*>(wlo + wrow * 96 + ks * 32 + kq * 8);
            }
#pragma unroll
            for (int t = 0; t < 3; ++t)
                acc[t] = __builtin_amdgcn_mfma_f32_16x16x32_bf16(Ah, Bh[t], acc[t], 0, 0, 0);
#pragma unroll
            for (int t = 0; t < 3; ++t)
                acc[t] = __builtin_amdgcn_mfma_f32_16x16x32_bf16(Ah, Bl[t], acc[t], 0, 0, 0);
        }
    }

    // ---- epilogue: C col(h)=lane&15, row(node)=kq*4+reg within stripe ----
    int gmin = 0, gnode[4];
    if (MODE == 2) {
        gmin = batch[blk0];
#pragma unroll
        for (int r = 0; r < 4; ++r) {
            int node = node0 + kq * 4 + r;
            gnode[r] = (node < N_NODES) ? batch[node] : -1;
        }
    }
#pragma unroll
    for (int t = 0; t < 3; ++t) {
        int h = (tbase + t) * 16 + col;
        if (h >= H) continue;
#pragma unroll
        for (int r = 0; r < 4; ++r) {
            int node = node0 + kq * 4 + r;
            if (node >= N_NODES) continue;
            float v = fmaxf(acc[t][r] + bv[t], 0.0f);
            if (MODE == 2) {
                int gl = gnode[r] - gmin;
                if (gl < SGROWS) atomicAdd(&SG[gl * 96 + h], v);
                else atomicAdd(&gs[gnode[r] * H + h], v);
            } else {
                __builtin_nontemporal_store(pack_hi(v), &ohi[(size_t)node * PSTRIDE + h]);
            }
        }
    }
    if (MODE == 2) {
        __syncthreads();
        for (int idx = tid; idx < SGROWS * 96; idx += 256) {
            int r = idx / 96, c = idx - r * 96;
            float s = SG[idx];
            if (c < H && s != 0.0f) atomicAdd(&gs[(gmin + r) * H + c], s);
        }
    }
}

// ================= pooling counts =================
__global__ __launch_bounds__(256) void pool_cnt_kernel(const int* __restrict__ batch,
                                                       float* __restrict__ gc) {
    int i = blockIdx.x * blockDim.x + threadIdx.x;
    if (i < N_NODES) atomicAdd(&gc[batch[i]], 1.0f);
}

// ================= MLP head =================
__global__ __launch_bounds__(64) void mlp_kernel(const float* __restrict__ gs,
                                                 const float* __restrict__ gc,
                                                 const float* __restrict__ fc1_w,
                                                 const float* __restrict__ fc1_b,
                                                 const float* __restrict__ fc2_w,
                                                 const float* __restrict__ fc2_b,
                                                 float* __restrict__ out) {
    int g = blockIdx.x;
    int t = threadIdx.x;
    __shared__ float h4[H];
    float inv = 1.0f / fmaxf(gc[g], 1.0f);
    for (int k = t; k < H; k += 64) h4[k] = gs[g * H + k] * inv;
    __syncthreads();
    float v = 0.0f;
    if (t < 32) {
        float acc = fc1_b[t];
#pragma unroll 6
        for (int k = 0; k < H; ++k) acc += h4[k] * fc1_w[t * H + k];
        v = fmaxf(acc, 0.0f) * fc2_w[t];
    }
    for (int off = 16; off; off >>= 1) v += __shfl_down(v, off, 32);
    if (t == 0) out[g] = v + fc2_b[0];
}

extern "C" void kernel_launch(void* const* d_in, const int* in_sizes, int n_in,
                              void* d_out, int out_size, void* d_ws, size_t ws_size,
                              hipStream_t stream) {
    const float* x     = (const float*)d_in[0];
    const int*   ei    = (const int*)d_in[1];
    const int*   batch = (const int*)d_in[2];
    const float* W1l = (const float*)d_in[3];
    const float* b1l = (const float*)d_in[4];
    const float* W1r = (const float*)d_in[5];
    const float* W2l = (const float*)d_in[6];
    const float* b2l = (const float*)d_in[7];
    const float* W2r = (const float*)d_in[8];
    const float* W3l = (const float*)d_in[9];
    const float* b3l = (const float*)d_in[10];
    const float* W3r = (const float*)d_in[11];
    const float* fc1_w = (const float*)d_in[12];
    const float* fc1_b = (const float*)d_in[13];
    const float* fc2_w = (const float*)d_in[14];
    const float* fc2_b = (const float*)d_in[15];

    const int* src = ei;
    const int* dst = ei + N_EDGES;

    // ---- workspace layout (~35 MB) ----
    const size_t NP = (size_t)N_NODES * PSTRIDE;
    unsigned short* P0h = (unsigned short*)d_ws;      // 9.2 MB
    unsigned short* P1h = P0h + NP;
    unsigned short* AGh = P1h + NP;
    unsigned short* csr = AGh + NP;                   // u16, 50000*64 = 6.4 MB
    int* cnt = (int*)(csr + (size_t)N_NODES * CAP);   // 200 KB
    unsigned short* wbuf = (unsigned short*)(cnt + N_NODES);
    float* gs = (float*)(wbuf + 6 * 2 * 96 * 96);
    float* gc = gs + N_GRAPHS * H;

    const unsigned short* wb1l = wbuf + 0 * 2 * 96 * 96;
    const unsigned short* wb1r = wbuf + 1 * 2 * 96 * 96;
    const unsigned short* wb2l = wbuf + 2 * 2 * 96 * 96;
    const unsigned short* wb2r = wbuf + 3 * 2 * 96 * 96;
    const unsigned short* wb3l = wbuf + 4 * 2 * 96 * 96;
    const unsigned short* wb3r = wbuf + 5 * 2 * 96 * 96;

    float* out = (float*)d_out;

    const int aggBlocks = N_NODES / 4;               // 12500

    convert_w_kernel<<<dim3(36, 6), 256, 0, stream>>>(W1l, W1r, W2l, W2r, W3l, W3r, wbuf);
    convert_x_kernel<<<NG32, 256, 0, stream>>>(x, P0h);

    // ---- one-pass bucket CSR build ----
    hipMemsetAsync(cnt, 0, N_NODES * sizeof(int), stream);
    fill_bucket_kernel<<<FCHUNKS * 8, 256, 0, stream>>>(src, dst, cnt, csr);

    // pool setup
    hipMemsetAsync(gs, 0, (N_GRAPHS * H + N_GRAPHS) * sizeof(float), stream);
    pool_cnt_kernel<<<(N_NODES + 255) / 256, 256, 0, stream>>>(batch, gc);

    // ---- layer 1: P0 -> P1 ----
    aggregate_kernel<<<aggBlocks, 256, 0, stream>>>((const unsigned*)P0h, cnt, csr,
                                                    (unsigned*)AGh);
    combine_kernel<1><<<NG32, 256, 0, stream>>>(AGh, P0h, wb1l, wb1r, b1l, P1h,
                                                nullptr, nullptr);
    // ---- layer 2: P1 -> P0 ----
    aggregate_kernel<<<aggBlocks, 256, 0, stream>>>((const unsigned*)P1h, cnt, csr,
                                                    (unsigned*)AGh);
    combine_kernel<1><<<NG32, 256, 0, stream>>>(AGh, P1h, wb2l, wb2r, b2l, P0h,
                                                nullptr, nullptr);
    // ---- layer 3: P0 -> fused pool into gs ----
    aggregate_kernel<<<aggBlocks, 256, 0, stream>>>((const unsigned*)P0h, cnt, csr,
                                                    (unsigned*)AGh);
    combine_kernel<2><<<NG32, 256, 0, stream>>>(AGh, P0h, wb3l, wb3r, b3l, nullptr,
                                                batch, gs);

    // ---- MLP head ----
    mlp_kernel<<<N_GRAPHS, 64, 0, stream>>>(gs, gc, fc1_w, fc1_b, fc2_w, fc2_b, out);
}

// Round 19
// 261.361 us; speedup vs baseline: 1.0363x; 1.0363x over previous
//
#include <hip/hip_runtime.h>
#include <hip/hip_bf16.h>

#define N_NODES 50000
#define N_EDGES 800000
#define N_GRAPHS 500
#define H 90
#define PSTRIDE 96     // plane row stride (u16) -> 192 B; 48 u32 per row
#define SGROWS 8
#define CAP 64         // bucket capacity; P(deg>64) ~ 1e-40 for Poisson(16)
#define NG32 ((N_NODES + 31) / 32)      // 1563

typedef __attribute__((ext_vector_type(8))) short bf16x8;
typedef __attribute__((ext_vector_type(8))) unsigned short u16x8;
typedef __attribute__((ext_vector_type(4))) float f32x4;

__device__ __forceinline__ void pack_split(float v, unsigned short& h16, unsigned short& l16) {
    unsigned u = __float_as_uint(v);
    unsigned hi = (u + 0x7fffu + ((u >> 16) & 1u)) & 0xffff0000u;
    float lo = v - __uint_as_float(hi);
    unsigned ul = __float_as_uint(lo);
    h16 = (unsigned short)(hi >> 16);
    l16 = (unsigned short)((ul + 0x7fffu + ((ul >> 16) & 1u)) >> 16);
}
__device__ __forceinline__ unsigned short pack_hi(float v) {   // RNE to bf16
    unsigned u = __float_as_uint(v);
    return (unsigned short)((u + 0x7fffu + ((u >> 16) & 1u)) >> 16);
}
__device__ __forceinline__ float bfu_lo(unsigned v) { return __uint_as_float(v << 16); }
__device__ __forceinline__ float bfu_hi(unsigned v) { return __uint_as_float(v & 0xffff0000u); }

// XOR-swizzled byte offset within LDS W tile (row stride 192 B)
__device__ __forceinline__ int wswz(int row, int byteInRow) {
    return (row * 192 + byteInRow) ^ ((row & 7) << 4);
}

// ================= conversions =================
__global__ __launch_bounds__(256) void convert_x_kernel(const float* __restrict__ x,
                                                        unsigned short* __restrict__ xh) {
    int n0 = blockIdx.x * 32;
    for (int idx = threadIdx.x; idx < 32 * PSTRIDE; idx += 256) {
        int r = idx / PSTRIDE, c = idx - r * PSTRIDE;
        int n = n0 + r;
        if (n >= N_NODES) continue;
        unsigned short h16 = 0;
        if (c < H) h16 = pack_hi(x[(size_t)n * H + c]);
        xh[(size_t)n * PSTRIDE + c] = h16;
    }
}

__global__ __launch_bounds__(256) void convert_w_kernel(const float* __restrict__ w0,
                                                        const float* __restrict__ w1,
                                                        const float* __restrict__ w2,
                                                        const float* __restrict__ w3,
                                                        const float* __restrict__ w4,
                                                        const float* __restrict__ w5,
                                                        unsigned short* __restrict__ wbuf) {
    int m = blockIdx.y;
    const float* src = (m == 0) ? w0 : (m == 1) ? w1 : (m == 2) ? w2
                     : (m == 3) ? w3 : (m == 4) ? w4 : w5;
    unsigned short* dhi = wbuf + (size_t)m * 2 * 96 * 96;
    unsigned short* dlo = dhi + 96 * 96;
    int idx = blockIdx.x * blockDim.x + threadIdx.x;
    if (idx < 96 * 96) {
        int r = idx / 96, c = idx - r * 96;
        float v = (r < H && c < H) ? src[r * H + c] : 0.0f;
        unsigned short h16, l16;
        pack_split(v, h16, l16);
        dhi[idx] = h16;
        dlo[idx] = l16;
    }
}

// ================= one-pass bucket CSR build (no deg/scan) =================
#define FCHUNKS 256
__global__ __launch_bounds__(256) void fill_bucket_kernel(const int* __restrict__ src,
                                                          const int* __restrict__ dst,
                                                          int* __restrict__ cnt,
                                                          unsigned short* __restrict__ csr) {
    const int PART_SZ = N_NODES / 8;
    const int ECH = (N_EDGES + FCHUNKS - 1) / FCHUNKS;
    int p = blockIdx.x & 7;
    int chunk = blockIdx.x >> 3;
    int e0 = chunk * ECH;
    int e1 = min(e0 + ECH, N_EDGES);
    int lo = p * PART_SZ;
    int hi = lo + PART_SZ;
    for (int e = e0 + threadIdx.x; e < e1; e += 256) {
        int d = dst[e];
        if (d >= lo && d < hi) {
            int pos = atomicAdd(&cnt[d], 1);
            if (pos < CAP) csr[(size_t)d * CAP + pos] = (unsigned short)src[e];
        }
    }
}

// ================= aggregation: 16-deep-unrolled bucket gather, hi-plane only =================
__global__ __launch_bounds__(256) void aggregate_kernel(const unsigned* __restrict__ xhi32,
                                                        const int* __restrict__ cnt,
                                                        const unsigned short* __restrict__ csr,
                                                        unsigned* __restrict__ ahi32) {
    int wv = threadIdx.x >> 6;
    int lane = threadIdx.x & 63;
    int n = blockIdx.x * 4 + wv;           // 12500*4 = 50000 exact

    bool act = lane < 45;
    int L = act ? lane : 44;
    int deg = cnt[n];
    int nd = min(deg, CAP);
    const unsigned short* row = csr + (size_t)n * CAP;

    float a0 = 0.0f, a1 = 0.0f;
    int j = 0;
    for (; j + 15 < nd; j += 16) {
        unsigned v[16];
#pragma unroll
        for (int q = 0; q < 16; ++q) v[q] = xhi32[(size_t)row[j + q] * 48 + L];
#pragma unroll
        for (int q = 0; q < 16; ++q) { a0 += bfu_lo(v[q]); a1 += bfu_hi(v[q]); }
    }
    for (; j + 7 < nd; j += 8) {
        unsigned v[8];
#pragma unroll
        for (int q = 0; q < 8; ++q) v[q] = xhi32[(size_t)row[j + q] * 48 + L];
#pragma unroll
        for (int q = 0; q < 8; ++q) { a0 += bfu_lo(v[q]); a1 += bfu_hi(v[q]); }
    }
    for (; j + 3 < nd; j += 4) {
        unsigned v[4];
#pragma unroll
        for (int q = 0; q < 4; ++q) v[q] = xhi32[(size_t)row[j + q] * 48 + L];
#pragma unroll
        for (int q = 0; q < 4; ++q) { a0 += bfu_lo(v[q]); a1 += bfu_hi(v[q]); }
    }
    for (; j < nd; ++j) {
        unsigned v = xhi32[(size_t)row[j] * 48 + L];
        a0 += bfu_lo(v);
        a1 += bfu_hi(v);
    }

    if (lane < 48) {
        unsigned vh = 0u;
        if (act) {
            float inv = 1.0f / (float)max(deg, 1);
            unsigned short h0 = pack_hi(a0 * inv);
            unsigned short h1 = pack_hi(a1 * inv);
            vh = (unsigned)h0 | ((unsigned)h1 << 16);
        }
        ahi32[(size_t)n * 48 + lane] = vh;   // lanes 45..47 zero cols 90..95
    }
}

// ================= combine: r15-proven (256 thr, A hi-only, W hi LDS + lo L2) =================
template<int MODE>
__global__ __launch_bounds__(256) void combine_kernel(
        const unsigned short* __restrict__ aghi,
        const unsigned short* __restrict__ xhi,
        const unsigned short* __restrict__ wl,   // hi plane then lo plane (96*96 each)
        const unsigned short* __restrict__ wr,
        const float* __restrict__ bias,
        unsigned short* __restrict__ ohi,
        const int* __restrict__ batch, float* __restrict__ gs) {
    __shared__ unsigned short sWlh[96 * 96];   // XOR-swizzled, row stride 192 B
    __shared__ unsigned short sWrh[96 * 96];
    __shared__ float SG[SGROWS * 96];

    const int tid = threadIdx.x;
    const int lane = tid & 63;
    const int wv = tid >> 6;
    const int nhalf = wv >> 1;
    const int hhalf = wv & 1;
    const int blk0 = blockIdx.x * 32;
    const int node0 = blk0 + nhalf * 16;
    const int col = lane & 15;
    const int kq = lane >> 4;
    const int tbase = hhalf * 3;
    const int nA = min(node0 + col, N_NODES - 1);

    // ---- hoist A loads (6 x 16B, in flight through staging + barrier) ----
    bf16x8 Gh[3], Xh[3];
#pragma unroll
    for (int ks = 0; ks < 3; ++ks) {
        size_t aoff = (size_t)nA * PSTRIDE + ks * 32 + kq * 8;
        Gh[ks] = *reinterpret_cast<const bf16x8*>(aghi + aoff);
        Xh[ks] = *reinterpret_cast<const bf16x8*>(xhi + aoff);
    }

    if (MODE == 2)
        for (int i = tid; i < SGROWS * 96; i += 256) SG[i] = 0.0f;

    // ---- stage BOTH W hi planes into LDS (2 x 18.4 KB) ----
    for (int idx = tid; idx < 96 * 12; idx += 256) {
        int r = idx / 12, c8 = idx - r * 12;
        u16x8 a = *reinterpret_cast<const u16x8*>(wl + r * 96 + c8 * 8);
        u16x8 b = *reinterpret_cast<const u16x8*>(wr + r * 96 + c8 * 8);
        *(u16x8*)((char*)sWlh + wswz(r, c8 * 16)) = a;
        *(u16x8*)((char*)sWrh + wswz(r, c8 * 16)) = b;
    }
    __syncthreads();   // the ONLY barrier in the main path

    float bv[3];
#pragma unroll
    for (int t = 0; t < 3; ++t) {
        int h = (tbase + t) * 16 + col;
        bv[t] = (h < H) ? bias[h] : 0.0f;
    }

    f32x4 acc[3] = {};

#pragma unroll
    for (int pass = 0; pass < 2; ++pass) {
        const unsigned short* wlo = (pass ? wr : wl) + 96 * 96;   // lo plane, from L2
        const unsigned short* sH = pass ? sWrh : sWlh;
#pragma unroll
        for (int ks = 0; ks < 3; ++ks) {
            const bf16x8 Ah = pass ? Xh[ks] : Gh[ks];
            const int kb = ks * 64 + kq * 16;    // byte offset in LDS row
            bf16x8 Bh[3], Bl[3];
#pragma unroll
            for (int t = 0; t < 3; ++t) {
                int wrow = (tbase + t) * 16 + col;
                Bh[t] = *(const bf16x8*)((const char*)sH + wswz(wrow, kb));
                Bl[t] = *reinterpret_cast<const bf16x8*>(wlo + wrow * 96 + ks * 32 + kq * 8);
            }
#pragma unroll
            for (int t = 0; t < 3; ++t)
                acc[t] = __builtin_amdgcn_mfma_f32_16x16x32_bf16(Ah, Bh[t], acc[t], 0, 0, 0);
#pragma unroll
            for (int t = 0; t < 3; ++t)
                acc[t] = __builtin_amdgcn_mfma_f32_16x16x32_bf16(Ah, Bl[t], acc[t], 0, 0, 0);
        }
    }

    // ---- epilogue: C col(h)=lane&15, row(node)=kq*4+reg within stripe ----
    int gmin = 0, gnode[4];
    if (MODE == 2) {
        gmin = batch[blk0];
#pragma unroll
        for (int r = 0; r < 4; ++r) {
            int node = node0 + kq * 4 + r;
            gnode[r] = (node < N_NODES) ? batch[node] : -1;
        }
    }
#pragma unroll
    for (int t = 0; t < 3; ++t) {
        int h = (tbase + t) * 16 + col;
        if (h >= H) continue;
#pragma unroll
        for (int r = 0; r < 4; ++r) {
            int node = node0 + kq * 4 + r;
            if (node >= N_NODES) continue;
            float v = fmaxf(acc[t][r] + bv[t], 0.0f);
            if (MODE == 2) {
                int gl = gnode[r] - gmin;
                if (gl < SGROWS) atomicAdd(&SG[gl * 96 + h], v);
                else atomicAdd(&gs[gnode[r] * H + h], v);
            } else {
                ohi[(size_t)node * PSTRIDE + h] = pack_hi(v);
            }
        }
    }
    if (MODE == 2) {
        __syncthreads();
        for (int idx = tid; idx < SGROWS * 96; idx += 256) {
            int r = idx / 96, c = idx - r * 96;
            float s = SG[idx];
            if (c < H && s != 0.0f) atomicAdd(&gs[(gmin + r) * H + c], s);
        }
    }
}

// ================= pooling counts =================
__global__ __launch_bounds__(256) void pool_cnt_kernel(const int* __restrict__ batch,
                                                       float* __restrict__ gc) {
    int i = blockIdx.x * blockDim.x + threadIdx.x;
    if (i < N_NODES) atomicAdd(&gc[batch[i]], 1.0f);
}

// ================= MLP head =================
__global__ __launch_bounds__(64) void mlp_kernel(const float* __restrict__ gs,
                                                 const float* __restrict__ gc,
                                                 const float* __restrict__ fc1_w,
                                                 const float* __restrict__ fc1_b,
                                                 const float* __restrict__ fc2_w,
                                                 const float* __restrict__ fc2_b,
                                                 float* __restrict__ out) {
    int g = blockIdx.x;
    int t = threadIdx.x;
    __shared__ float h4[H];
    float inv = 1.0f / fmaxf(gc[g], 1.0f);
    for (int k = t; k < H; k += 64) h4[k] = gs[g * H + k] * inv;
    __syncthreads();
    float v = 0.0f;
    if (t < 32) {
        float acc = fc1_b[t];
#pragma unroll 6
        for (int k = 0; k < H; ++k) acc += h4[k] * fc1_w[t * H + k];
        v = fmaxf(acc, 0.0f) * fc2_w[t];
    }
    for (int off = 16; off; off >>= 1) v += __shfl_down(v, off, 32);
    if (t == 0) out[g] = v + fc2_b[0];
}

extern "C" void kernel_launch(void* const* d_in, const int* in_sizes, int n_in,
                              void* d_out, int out_size, void* d_ws, size_t ws_size,
                              hipStream_t stream) {
    const float* x     = (const float*)d_in[0];
    const int*   ei    = (const int*)d_in[1];
    const int*   batch = (const int*)d_in[2];
    const float* W1l = (const float*)d_in[3];
    const float* b1l = (const float*)d_in[4];
    const float* W1r = (const float*)d_in[5];
    const float* W2l = (const float*)d_in[6];
    const float* b2l = (const float*)d_in[7];
    const float* W2r = (const float*)d_in[8];
    const float* W3l = (const float*)d_in[9];
    const float* b3l = (const float*)d_in[10];
    const float* W3r = (const float*)d_in[11];
    const float* fc1_w = (const float*)d_in[12];
    const float* fc1_b = (const float*)d_in[13];
    const float* fc2_w = (const float*)d_in[14];
    const float* fc2_b = (const float*)d_in[15];

    const int* src = ei;
    const int* dst = ei + N_EDGES;

    // ---- workspace layout (~35 MB) ----
    const size_t NP = (size_t)N_NODES * PSTRIDE;
    unsigned short* P0h = (unsigned short*)d_ws;      // 9.2 MB
    unsigned short* P1h = P0h + NP;
    unsigned short* AGh = P1h + NP;
    unsigned short* csr = AGh + NP;                   // u16, 50000*64 = 6.4 MB
    int* cnt = (int*)(csr + (size_t)N_NODES * CAP);   // 200 KB
    unsigned short* wbuf = (unsigned short*)(cnt + N_NODES);
    float* gs = (float*)(wbuf + 6 * 2 * 96 * 96);
    float* gc = gs + N_GRAPHS * H;

    const unsigned short* wb1l = wbuf + 0 * 2 * 96 * 96;
    const unsigned short* wb1r = wbuf + 1 * 2 * 96 * 96;
    const unsigned short* wb2l = wbuf + 2 * 2 * 96 * 96;
    const unsigned short* wb2r = wbuf + 3 * 2 * 96 * 96;
    const unsigned short* wb3l = wbuf + 4 * 2 * 96 * 96;
    const unsigned short* wb3r = wbuf + 5 * 2 * 96 * 96;

    float* out = (float*)d_out;

    const int aggBlocks = N_NODES / 4;               // 12500

    convert_w_kernel<<<dim3(36, 6), 256, 0, stream>>>(W1l, W1r, W2l, W2r, W3l, W3r, wbuf);
    convert_x_kernel<<<NG32, 256, 0, stream>>>(x, P0h);

    // ---- one-pass bucket CSR build ----
    hipMemsetAsync(cnt, 0, N_NODES * sizeof(int), stream);
    fill_bucket_kernel<<<FCHUNKS * 8, 256, 0, stream>>>(src, dst, cnt, csr);

    // pool setup
    hipMemsetAsync(gs, 0, (N_GRAPHS * H + N_GRAPHS) * sizeof(float), stream);
    pool_cnt_kernel<<<(N_NODES + 255) / 256, 256, 0, stream>>>(batch, gc);

    // ---- layer 1: P0 -> P1 ----
    aggregate_kernel<<<aggBlocks, 256, 0, stream>>>((const unsigned*)P0h, cnt, csr,
                                                    (unsigned*)AGh);
    combine_kernel<1><<<NG32, 256, 0, stream>>>(AGh, P0h, wb1l, wb1r, b1l, P1h,
                                                nullptr, nullptr);
    // ---- layer 2: P1 -> P0 ----
    aggregate_kernel<<<aggBlocks, 256, 0, stream>>>((const unsigned*)P1h, cnt, csr,
                                                    (unsigned*)AGh);
    combine_kernel<1><<<NG32, 256, 0, stream>>>(AGh, P1h, wb2l, wb2r, b2l, P0h,
                                                nullptr, nullptr);
    // ---- layer 3: P0 -> fused pool into gs ----
    aggregate_kernel<<<aggBlocks, 256, 0, stream>>>((const unsigned*)P0h, cnt, csr,
                                                    (unsigned*)AGh);
    combine_kernel<2><<<NG32, 256, 0, stream>>>(AGh, P0h, wb3l, wb3r, b3l, nullptr,
                                                batch, gs);

    // ---- MLP head ----
    mlp_kernel<<<N_GRAPHS, 64, 0, stream>>>(gs, gc, fc1_w, fc1_b, fc2_w, fc2_b, out);
}

// Round 20
// 255.512 us; speedup vs baseline: 1.0600x; 1.0229x over previous
//
#include <hip/hip_runtime.h>
#include <hip/hip_bf16.h>

#define N_NODES 50000
#define N_EDGES 800000
#define N_GRAPHS 500
#define H 90
#define PSTRIDE 96     // plane row stride (u16) -> 192 B; 48 u32 per row
#define SGROWS 8
#define CAP 64         // bucket capacity; P(deg>64) ~ 1e-40 for Poisson(16)
#define NG32 ((N_NODES + 31) / 32)      // 1563 combine groups
#define GSTRIDE ((NG32 + 1) / 2)        // 782: block b handles groups b and b+782

typedef __attribute__((ext_vector_type(8))) short bf16x8;
typedef __attribute__((ext_vector_type(8))) unsigned short u16x8;
typedef __attribute__((ext_vector_type(4))) float f32x4;

__device__ __forceinline__ void pack_split(float v, unsigned short& h16, unsigned short& l16) {
    unsigned u = __float_as_uint(v);
    unsigned hi = (u + 0x7fffu + ((u >> 16) & 1u)) & 0xffff0000u;
    float lo = v - __uint_as_float(hi);
    unsigned ul = __float_as_uint(lo);
    h16 = (unsigned short)(hi >> 16);
    l16 = (unsigned short)((ul + 0x7fffu + ((ul >> 16) & 1u)) >> 16);
}
__device__ __forceinline__ unsigned short pack_hi(float v) {   // RNE to bf16
    unsigned u = __float_as_uint(v);
    return (unsigned short)((u + 0x7fffu + ((u >> 16) & 1u)) >> 16);
}
__device__ __forceinline__ float bfu_lo(unsigned v) { return __uint_as_float(v << 16); }
__device__ __forceinline__ float bfu_hi(unsigned v) { return __uint_as_float(v & 0xffff0000u); }

// XOR-swizzled byte offset within LDS W tile (row stride 192 B)
__device__ __forceinline__ int wswz(int row, int byteInRow) {
    return (row * 192 + byteInRow) ^ ((row & 7) << 4);
}

// ================= conversions =================
__global__ __launch_bounds__(256) void convert_x_kernel(const float* __restrict__ x,
                                                        unsigned short* __restrict__ xh) {
    int n0 = blockIdx.x * 32;
    for (int idx = threadIdx.x; idx < 32 * PSTRIDE; idx += 256) {
        int r = idx / PSTRIDE, c = idx - r * PSTRIDE;
        int n = n0 + r;
        if (n >= N_NODES) continue;
        unsigned short h16 = 0;
        if (c < H) h16 = pack_hi(x[(size_t)n * H + c]);
        xh[(size_t)n * PSTRIDE + c] = h16;
    }
}

__global__ __launch_bounds__(256) void convert_w_kernel(const float* __restrict__ w0,
                                                        const float* __restrict__ w1,
                                                        const float* __restrict__ w2,
                                                        const float* __restrict__ w3,
                                                        const float* __restrict__ w4,
                                                        const float* __restrict__ w5,
                                                        unsigned short* __restrict__ wbuf) {
    int m = blockIdx.y;
    const float* src = (m == 0) ? w0 : (m == 1) ? w1 : (m == 2) ? w2
                     : (m == 3) ? w3 : (m == 4) ? w4 : w5;
    unsigned short* dhi = wbuf + (size_t)m * 2 * 96 * 96;
    unsigned short* dlo = dhi + 96 * 96;
    int idx = blockIdx.x * blockDim.x + threadIdx.x;
    if (idx < 96 * 96) {
        int r = idx / 96, c = idx - r * 96;
        float v = (r < H && c < H) ? src[r * H + c] : 0.0f;
        unsigned short h16, l16;
        pack_split(v, h16, l16);
        dhi[idx] = h16;
        dlo[idx] = l16;
    }
}

// ================= one-pass bucket CSR build (no deg/scan) =================
#define FCHUNKS 256
__global__ __launch_bounds__(256) void fill_bucket_kernel(const int* __restrict__ src,
                                                          const int* __restrict__ dst,
                                                          int* __restrict__ cnt,
                                                          unsigned short* __restrict__ csr) {
    const int PART_SZ = N_NODES / 8;
    const int ECH = (N_EDGES + FCHUNKS - 1) / FCHUNKS;
    int p = blockIdx.x & 7;
    int chunk = blockIdx.x >> 3;
    int e0 = chunk * ECH;
    int e1 = min(e0 + ECH, N_EDGES);
    int lo = p * PART_SZ;
    int hi = lo + PART_SZ;
    for (int e = e0 + threadIdx.x; e < e1; e += 256) {
        int d = dst[e];
        if (d >= lo && d < hi) {
            int pos = atomicAdd(&cnt[d], 1);
            if (pos < CAP) csr[(size_t)d * CAP + pos] = (unsigned short)src[e];
        }
    }
}

// ================= aggregation: 16-deep-unrolled bucket gather, hi-plane only =================
__global__ __launch_bounds__(256) void aggregate_kernel(const unsigned* __restrict__ xhi32,
                                                        const int* __restrict__ cnt,
                                                        const unsigned short* __restrict__ csr,
                                                        unsigned* __restrict__ ahi32) {
    int wv = threadIdx.x >> 6;
    int lane = threadIdx.x & 63;
    int n = blockIdx.x * 4 + wv;           // 12500*4 = 50000 exact

    bool act = lane < 45;
    int L = act ? lane : 44;
    int deg = cnt[n];
    int nd = min(deg, CAP);
    const unsigned short* row = csr + (size_t)n * CAP;

    float a0 = 0.0f, a1 = 0.0f;
    int j = 0;
    for (; j + 15 < nd; j += 16) {
        unsigned v[16];
#pragma unroll
        for (int q = 0; q < 16; ++q) v[q] = xhi32[(size_t)row[j + q] * 48 + L];
#pragma unroll
        for (int q = 0; q < 16; ++q) { a0 += bfu_lo(v[q]); a1 += bfu_hi(v[q]); }
    }
    for (; j + 7 < nd; j += 8) {
        unsigned v[8];
#pragma unroll
        for (int q = 0; q < 8; ++q) v[q] = xhi32[(size_t)row[j + q] * 48 + L];
#pragma unroll
        for (int q = 0; q < 8; ++q) { a0 += bfu_lo(v[q]); a1 += bfu_hi(v[q]); }
    }
    for (; j + 3 < nd; j += 4) {
        unsigned v[4];
#pragma unroll
        for (int q = 0; q < 4; ++q) v[q] = xhi32[(size_t)row[j + q] * 48 + L];
#pragma unroll
        for (int q = 0; q < 4; ++q) { a0 += bfu_lo(v[q]); a1 += bfu_hi(v[q]); }
    }
    for (; j < nd; ++j) {
        unsigned v = xhi32[(size_t)row[j] * 48 + L];
        a0 += bfu_lo(v);
        a1 += bfu_hi(v);
    }

    if (lane < 48) {
        unsigned vh = 0u;
        if (act) {
            float inv = 1.0f / (float)max(deg, 1);
            unsigned short h0 = pack_hi(a0 * inv);
            unsigned short h1 = pack_hi(a1 * inv);
            vh = (unsigned)h0 | ((unsigned)h1 << 16);
        }
        ahi32[(size_t)n * 48 + lane] = vh;   // lanes 45..47 zero cols 90..95
    }
}

// ================= combine: PAIR-GROUP (2 groups/block, shared W, 2x ILP) =================
// Block b handles groups b and b+GSTRIDE. 12 A-loads hoisted at entry; W staged once;
// each W fragment feeds MFMAs of BOTH groups (halves W traffic, doubles work/load).
template<int MODE>
__global__ __launch_bounds__(256) void combine_kernel(
        const unsigned short* __restrict__ aghi,
        const unsigned short* __restrict__ xhi,
        const unsigned short* __restrict__ wl,   // hi plane then lo plane (96*96 each)
        const unsigned short* __restrict__ wr,
        const float* __restrict__ bias,
        unsigned short* __restrict__ ohi,
        const int* __restrict__ batch, float* __restrict__ gs) {
    __shared__ unsigned short sWlh[96 * 96];   // XOR-swizzled, row stride 192 B
    __shared__ unsigned short sWrh[96 * 96];
    __shared__ float SG[SGROWS * 96];

    const int tid = threadIdx.x;
    const int lane = tid & 63;
    const int wv = tid >> 6;
    const int nhalf = wv >> 1;
    const int hhalf = wv & 1;
    const int col = lane & 15;
    const int kq = lane >> 4;
    const int tbase = hhalf * 3;

    const int blk1 = blockIdx.x * 32;
    const int blk2 = (blockIdx.x + GSTRIDE) * 32;
    const int node1 = blk1 + nhalf * 16;
    const int node2 = blk2 + nhalf * 16;
    const int nA1 = min(node1 + col, N_NODES - 1);
    const int nA2 = min(node2 + col, N_NODES - 1);

    // ---- hoist ALL A loads for BOTH groups (12 x 16B, independent chains) ----
    bf16x8 Gh1[3], Xh1[3], Gh2[3], Xh2[3];
#pragma unroll
    for (int ks = 0; ks < 3; ++ks) {
        size_t o1 = (size_t)nA1 * PSTRIDE + ks * 32 + kq * 8;
        size_t o2 = (size_t)nA2 * PSTRIDE + ks * 32 + kq * 8;
        Gh1[ks] = *reinterpret_cast<const bf16x8*>(aghi + o1);
        Xh1[ks] = *reinterpret_cast<const bf16x8*>(xhi + o1);
        Gh2[ks] = *reinterpret_cast<const bf16x8*>(aghi + o2);
        Xh2[ks] = *reinterpret_cast<const bf16x8*>(xhi + o2);
    }

    if (MODE == 2)
        for (int i = tid; i < SGROWS * 96; i += 256) SG[i] = 0.0f;

    // ---- stage BOTH W hi planes into LDS (once, shared by both groups) ----
    for (int idx = tid; idx < 96 * 12; idx += 256) {
        int r = idx / 12, c8 = idx - r * 12;
        u16x8 a = *reinterpret_cast<const u16x8*>(wl + r * 96 + c8 * 8);
        u16x8 b = *reinterpret_cast<const u16x8*>(wr + r * 96 + c8 * 8);
        *(u16x8*)((char*)sWlh + wswz(r, c8 * 16)) = a;
        *(u16x8*)((char*)sWrh + wswz(r, c8 * 16)) = b;
    }
    __syncthreads();

    float bv[3];
#pragma unroll
    for (int t = 0; t < 3; ++t) {
        int h = (tbase + t) * 16 + col;
        bv[t] = (h < H) ? bias[h] : 0.0f;
    }

    f32x4 acc1[3] = {}, acc2[3] = {};

#pragma unroll
    for (int pass = 0; pass < 2; ++pass) {
        const unsigned short* wlo = (pass ? wr : wl) + 96 * 96;   // lo plane, from L2
        const unsigned short* sH = pass ? sWrh : sWlh;
#pragma unroll
        for (int ks = 0; ks < 3; ++ks) {
            const bf16x8 A1 = pass ? Xh1[ks] : Gh1[ks];
            const bf16x8 A2 = pass ? Xh2[ks] : Gh2[ks];
            const int kb = ks * 64 + kq * 16;    // byte offset in LDS row
            bf16x8 Bh[3], Bl[3];
#pragma unroll
            for (int t = 0; t < 3; ++t) {
                int wrow = (tbase + t) * 16 + col;
                Bh[t] = *(const bf16x8*)((const char*)sH + wswz(wrow, kb));
                Bl[t] = *reinterpret_cast<const bf16x8*>(wlo + wrow * 96 + ks * 32 + kq * 8);
            }
#pragma unroll
            for (int t = 0; t < 3; ++t) {
                acc1[t] = __builtin_amdgcn_mfma_f32_16x16x32_bf16(A1, Bh[t], acc1[t], 0, 0, 0);
                acc2[t] = __builtin_amdgcn_mfma_f32_16x16x32_bf16(A2, Bh[t], acc2[t], 0, 0, 0);
            }
#pragma unroll
            for (int t = 0; t < 3; ++t) {
                acc1[t] = __builtin_amdgcn_mfma_f32_16x16x32_bf16(A1, Bl[t], acc1[t], 0, 0, 0);
                acc2[t] = __builtin_amdgcn_mfma_f32_16x16x32_bf16(A2, Bl[t], acc2[t], 0, 0, 0);
            }
        }
    }

    // ---- epilogue group 1 ----
    {
        int gmin = 0, gnode[4];
        if (MODE == 2) {
            gmin = batch[min(blk1, N_NODES - 1)];
#pragma unroll
            for (int r = 0; r < 4; ++r) {
                int node = node1 + kq * 4 + r;
                gnode[r] = (node < N_NODES) ? batch[node] : -1;
            }
        }
#pragma unroll
        for (int t = 0; t < 3; ++t) {
            int h = (tbase + t) * 16 + col;
            if (h >= H) continue;
#pragma unroll
            for (int r = 0; r < 4; ++r) {
                int node = node1 + kq * 4 + r;
                if (node >= N_NODES) continue;
                float v = fmaxf(acc1[t][r] + bv[t], 0.0f);
                if (MODE == 2) {
                    int gl = gnode[r] - gmin;
                    if (gl < SGROWS) atomicAdd(&SG[gl * 96 + h], v);
                    else atomicAdd(&gs[gnode[r] * H + h], v);
                } else {
                    ohi[(size_t)node * PSTRIDE + h] = pack_hi(v);
                }
            }
        }
        if (MODE == 2) {
            __syncthreads();
            for (int idx = tid; idx < SGROWS * 96; idx += 256) {
                int r = idx / 96, c = idx - r * 96;
                float s = SG[idx];
                if (c < H && s != 0.0f) atomicAdd(&gs[(gmin + r) * H + c], s);
            }
            __syncthreads();
            for (int i = tid; i < SGROWS * 96; i += 256) SG[i] = 0.0f;
            __syncthreads();
        }
    }

    // ---- epilogue group 2 ----
    {
        int gmin = 0, gnode[4];
        if (MODE == 2) {
            gmin = batch[min(blk2, N_NODES - 1)];
#pragma unroll
            for (int r = 0; r < 4; ++r) {
                int node = node2 + kq * 4 + r;
                gnode[r] = (node < N_NODES) ? batch[node] : -1;
            }
        }
#pragma unroll
        for (int t = 0; t < 3; ++t) {
            int h = (tbase + t) * 16 + col;
            if (h >= H) continue;
#pragma unroll
            for (int r = 0; r < 4; ++r) {
                int node = node2 + kq * 4 + r;
                if (node >= N_NODES) continue;
                float v = fmaxf(acc2[t][r] + bv[t], 0.0f);
                if (MODE == 2) {
                    int gl = gnode[r] - gmin;
                    if (gl < SGROWS) atomicAdd(&SG[gl * 96 + h], v);
                    else atomicAdd(&gs[gnode[r] * H + h], v);
                } else {
                    ohi[(size_t)node * PSTRIDE + h] = pack_hi(v);
                }
            }
        }
        if (MODE == 2) {
            __syncthreads();
            for (int idx = tid; idx < SGROWS * 96; idx += 256) {
                int r = idx / 96, c = idx - r * 96;
                float s = SG[idx];
                if (c < H && s != 0.0f) atomicAdd(&gs[(gmin + r) * H + c], s);
            }
        }
    }
}

// ================= pooling counts =================
__global__ __launch_bounds__(256) void pool_cnt_kernel(const int* __restrict__ batch,
                                                       float* __restrict__ gc) {
    int i = blockIdx.x * blockDim.x + threadIdx.x;
    if (i < N_NODES) atomicAdd(&gc[batch[i]], 1.0f);
}

// ================= MLP head =================
__global__ __launch_bounds__(64) void mlp_kernel(const float* __restrict__ gs,
                                                 const float* __restrict__ gc,
                                                 const float* __restrict__ fc1_w,
                                                 const float* __restrict__ fc1_b,
                                                 const float* __restrict__ fc2_w,
                                                 const float* __restrict__ fc2_b,
                                                 float* __restrict__ out) {
    int g = blockIdx.x;
    int t = threadIdx.x;
    __shared__ float h4[H];
    float inv = 1.0f / fmaxf(gc[g], 1.0f);
    for (int k = t; k < H; k += 64) h4[k] = gs[g * H + k] * inv;
    __syncthreads();
    float v = 0.0f;
    if (t < 32) {
        float acc = fc1_b[t];
#pragma unroll 6
        for (int k = 0; k < H; ++k) acc += h4[k] * fc1_w[t * H + k];
        v = fmaxf(acc, 0.0f) * fc2_w[t];
    }
    for (int off = 16; off; off >>= 1) v += __shfl_down(v, off, 32);
    if (t == 0) out[g] = v + fc2_b[0];
}

extern "C" void kernel_launch(void* const* d_in, const int* in_sizes, int n_in,
                              void* d_out, int out_size, void* d_ws, size_t ws_size,
                              hipStream_t stream) {
    const float* x     = (const float*)d_in[0];
    const int*   ei    = (const int*)d_in[1];
    const int*   batch = (const int*)d_in[2];
    const float* W1l = (const float*)d_in[3];
    const float* b1l = (const float*)d_in[4];
    const float* W1r = (const float*)d_in[5];
    const float* W2l = (const float*)d_in[6];
    const float* b2l = (const float*)d_in[7];
    const float* W2r = (const float*)d_in[8];
    const float* W3l = (const float*)d_in[9];
    const float* b3l = (const float*)d_in[10];
    const float* W3r = (const float*)d_in[11];
    const float* fc1_w = (const float*)d_in[12];
    const float* fc1_b = (const float*)d_in[13];
    const float* fc2_w = (const float*)d_in[14];
    const float* fc2_b = (const float*)d_in[15];

    const int* src = ei;
    const int* dst = ei + N_EDGES;

    // ---- workspace layout (~35 MB) ----
    const size_t NP = (size_t)N_NODES * PSTRIDE;
    unsigned short* P0h = (unsigned short*)d_ws;      // 9.2 MB
    unsigned short* P1h = P0h + NP;
    unsigned short* AGh = P1h + NP;
    unsigned short* csr = AGh + NP;                   // u16, 50000*64 = 6.4 MB
    int* cnt = (int*)(csr + (size_t)N_NODES * CAP);   // 200 KB
    unsigned short* wbuf = (unsigned short*)(cnt + N_NODES);
    float* gs = (float*)(wbuf + 6 * 2 * 96 * 96);
    float* gc = gs + N_GRAPHS * H;

    const unsigned short* wb1l = wbuf + 0 * 2 * 96 * 96;
    const unsigned short* wb1r = wbuf + 1 * 2 * 96 * 96;
    const unsigned short* wb2l = wbuf + 2 * 2 * 96 * 96;
    const unsigned short* wb2r = wbuf + 3 * 2 * 96 * 96;
    const unsigned short* wb3l = wbuf + 4 * 2 * 96 * 96;
    const unsigned short* wb3r = wbuf + 5 * 2 * 96 * 96;

    float* out = (float*)d_out;

    const int aggBlocks = N_NODES / 4;               // 12500
    const int NG32c = (N_NODES + 31) / 32;           // 1563

    convert_w_kernel<<<dim3(36, 6), 256, 0, stream>>>(W1l, W1r, W2l, W2r, W3l, W3r, wbuf);
    convert_x_kernel<<<NG32c, 256, 0, stream>>>(x, P0h);

    // ---- one-pass bucket CSR build ----
    hipMemsetAsync(cnt, 0, N_NODES * sizeof(int), stream);
    fill_bucket_kernel<<<FCHUNKS * 8, 256, 0, stream>>>(src, dst, cnt, csr);

    // pool setup
    hipMemsetAsync(gs, 0, (N_GRAPHS * H + N_GRAPHS) * sizeof(float), stream);
    pool_cnt_kernel<<<(N_NODES + 255) / 256, 256, 0, stream>>>(batch, gc);

    // ---- layer 1: P0 -> P1 ----
    aggregate_kernel<<<aggBlocks, 256, 0, stream>>>((const unsigned*)P0h, cnt, csr,
                                                    (unsigned*)AGh);
    combine_kernel<1><<<GSTRIDE, 256, 0, stream>>>(AGh, P0h, wb1l, wb1r, b1l, P1h,
                                                   nullptr, nullptr);
    // ---- layer 2: P1 -> P0 ----
    aggregate_kernel<<<aggBlocks, 256, 0, stream>>>((const unsigned*)P1h, cnt, csr,
                                                    (unsigned*)AGh);
    combine_kernel<1><<<GSTRIDE, 256, 0, stream>>>(AGh, P1h, wb2l, wb2r, b2l, P0h,
                                                   nullptr, nullptr);
    // ---- layer 3: P0 -> fused pool into gs ----
    aggregate_kernel<<<aggBlocks, 256, 0, stream>>>((const unsigned*)P0h, cnt, csr,
                                                    (unsigned*)AGh);
    combine_kernel<2><<<GSTRIDE, 256, 0, stream>>>(AGh, P0h, wb3l, wb3r, b3l, nullptr,
                                                   batch, gs);

    // ---- MLP head ----
    mlp_kernel<<<N_GRAPHS, 64, 0, stream>>>(gs, gc, fc1_w, fc1_b, fc2_w, fc2_b, out);
}